// Round 1
// baseline (563.107 us; speedup 1.0000x reference)
//
#include <hip/hip_runtime.h>
#include <stdint.h>

#define S_ 1024
#define D_ 64
#define B_ 64

typedef short short8 __attribute__((ext_vector_type(8)));
typedef unsigned short ushort8 __attribute__((ext_vector_type(8)));
typedef float f32x4 __attribute__((ext_vector_type(4)));

__device__ __forceinline__ unsigned short f2bf(float x) {
    uint32_t u = __builtin_bit_cast(uint32_t, x);
    return (unsigned short)((u + 0x7FFFu + ((u >> 16) & 1u)) >> 16);
}
__device__ __forceinline__ float bf2f(unsigned short b) {
    return __builtin_bit_cast(float, ((uint32_t)b) << 16);
}
__device__ __forceinline__ uint32_t pack2(float a, float b) {
    return (uint32_t)f2bf(a) | ((uint32_t)f2bf(b) << 16);
}
// XOR-swizzled index into the 16x1024 bf16 score buffer (16B-chunk swizzle by row)
__device__ __forceinline__ int scidx(int row, int k) {
    return (((row << 10) + (k & ~7)) ^ ((row & 7) << 3)) + (k & 7);
}

// ---------------- K1: qk[b,q,k] = Q[b,q,:].K[b,k,:]  (writes f32 into attn region)
__global__ __launch_bounds__(256) void k1_qk(const float* __restrict__ Q,
                                             const float* __restrict__ Kk,
                                             float* __restrict__ qk) {
    __shared__ __align__(16) unsigned short Qs[128][72];
    __shared__ __align__(16) unsigned short Ks[128][72];
    const int bx = blockIdx.x;
    const int b  = bx >> 6;
    const int q0 = ((bx >> 3) & 7) << 7;
    const int k0 = (bx & 7) << 7;
    const int t  = threadIdx.x;
#pragma unroll
    for (int i = 0; i < 8; ++i) {
        int f = (i << 8) + t;
        int row = f >> 4, c = (f & 15) << 2;
        float4 v = *reinterpret_cast<const float4*>(&Q[((size_t)(b * S_ + q0 + row) << 6) + c]);
        *reinterpret_cast<uint2*>(&Qs[row][c]) = make_uint2(pack2(v.x, v.y), pack2(v.z, v.w));
        float4 u = *reinterpret_cast<const float4*>(&Kk[((size_t)(b * S_ + k0 + row) << 6) + c]);
        *reinterpret_cast<uint2*>(&Ks[row][c]) = make_uint2(pack2(u.x, u.y), pack2(u.z, u.w));
    }
    __syncthreads();
    const int l = t & 63, w = t >> 6, lr = l & 15, lg = l >> 4;
    short8 a[2][2];
#pragma unroll
    for (int mi = 0; mi < 2; ++mi)
#pragma unroll
        for (int h = 0; h < 2; ++h)
            a[mi][h] = *reinterpret_cast<const short8*>(&Qs[((w * 2 + mi) << 4) + lr][h * 32 + lg * 8]);
    f32x4 acc[2][8] = {};
#pragma unroll
    for (int n = 0; n < 8; ++n) {
        short8 b0 = *reinterpret_cast<const short8*>(&Ks[(n << 4) + lr][lg * 8]);
        short8 b1 = *reinterpret_cast<const short8*>(&Ks[(n << 4) + lr][32 + lg * 8]);
#pragma unroll
        for (int mi = 0; mi < 2; ++mi) {
            acc[mi][n] = __builtin_amdgcn_mfma_f32_16x16x32_bf16(a[mi][0], b0, acc[mi][n], 0, 0, 0);
            acc[mi][n] = __builtin_amdgcn_mfma_f32_16x16x32_bf16(a[mi][1], b1, acc[mi][n], 0, 0, 0);
        }
    }
#pragma unroll
    for (int mi = 0; mi < 2; ++mi)
#pragma unroll
        for (int n = 0; n < 8; ++n)
#pragma unroll
            for (int r = 0; r < 4; ++r) {
                int qq = q0 + ((w * 2 + mi) << 4) + (lg << 2) + r;
                int kc = k0 + (n << 4) + lr;
                qk[((size_t)(b * S_ + qq) << 10) + kc] = acc[mi][n][r];
            }
}

// in-register 4x4 transpose (lanes l, l^16, l^32, l^48) then b64 LDS store: T[d][k]
__device__ __forceinline__ void tpose_store(unsigned short (*Tls)[72], float4 p,
                                            int i, int t) {
    const int l = t & 63, w = t >> 6, lr = l & 15, lg = l >> 4;
    float v0 = p.x, v1 = p.y, v2 = p.z, v3 = p.w;
    float y0 = __shfl_xor(v0, 16), y1 = __shfl_xor(v1, 16),
          y2 = __shfl_xor(v2, 16), y3 = __shfl_xor(v3, 16);
    bool o = (lg & 1);
    float n0 = o ? y1 : v0, n1 = o ? v1 : y0, n2 = o ? y3 : v2, n3 = o ? v3 : y2;
    float z0 = __shfl_xor(n0, 32), z1 = __shfl_xor(n1, 32),
          z2 = __shfl_xor(n2, 32), z3 = __shfl_xor(n3, 32);
    bool h = (lg & 2);
    float T0 = h ? z2 : n0, T1 = h ? z3 : n1, T2 = h ? n2 : z0, T3 = h ? n3 : z1;
    int d = (lr << 2) + lg, kb = (i << 4) + (w << 2);
    *reinterpret_cast<uint2*>(&Tls[d][kb]) = make_uint2(pack2(T0, T1), pack2(T2, T3));
}

// ---------------- K2: per (q, 16-batch group): rel scores + softmax + attn + rel_qkv
__global__ __launch_bounds__(256) void k2_mid(const float* __restrict__ Q,
                                              const float* __restrict__ AK,
                                              const float* __restrict__ AV,
                                              float* __restrict__ attn,
                                              float* __restrict__ outp) {
    __shared__ __align__(16) unsigned short Sc[16 * 1024];
    __shared__ __align__(16) unsigned short Qs[16][72];
    __shared__ __align__(16) unsigned short Ak[64][72];
    __shared__ float invs[16];
    const float SCL = 0.18033688011112042f;  // log2(e)/8
    const int q  = blockIdx.x >> 2;
    const int b0 = (blockIdx.x & 3) << 4;
    const int t  = threadIdx.x;
    const int l = t & 63, w = t >> 6, lr = l & 15, lg = l >> 4;

    {   // Qs (pre-scaled by SCL)
        int row = t >> 4, c = (t & 15) << 2;
        float4 v = *reinterpret_cast<const float4*>(&Q[((size_t)((b0 + row) * S_ + q) << 6) + c]);
        *reinterpret_cast<uint2*>(&Qs[row][c]) =
            make_uint2(pack2(v.x * SCL, v.y * SCL), pack2(v.z * SCL, v.w * SCL));
    }
#pragma unroll
    for (int i = 0; i < 16; ++i) {   // init Sc = qk * SCL
        int f = (i << 8) + t;
        int row = f >> 8, k = (f & 255) << 2;
        float4 v = *reinterpret_cast<const float4*>(&attn[((size_t)((b0 + row) * S_ + q) << 10) + k]);
        *reinterpret_cast<uint2*>(&Sc[scidx(row, k)]) =
            make_uint2(pack2(v.x * SCL, v.y * SCL), pack2(v.z * SCL, v.w * SCL));
    }
    __syncthreads();

    // ---- phase A: scores += (Q*SCL) . a_key[q]^T
    short8 qa0 = *reinterpret_cast<const short8*>(&Qs[lr][lg * 8]);
    short8 qa1 = *reinterpret_cast<const short8*>(&Qs[lr][32 + lg * 8]);
    const float* akbase = &AK[(size_t)q << 16];
    float4 pf[4];
#pragma unroll
    for (int i = 0; i < 4; ++i) {
        int f = (i << 8) + t;
        pf[i] = *reinterpret_cast<const float4*>(&akbase[((size_t)(f >> 4) << 6) + ((f & 15) << 2)]);
    }
    for (int tt = 0; tt < 16; ++tt) {
        __syncthreads();
#pragma unroll
        for (int i = 0; i < 4; ++i) {
            int f = (i << 8) + t;
            int row = f >> 4, c = (f & 15) << 2;
            *reinterpret_cast<uint2*>(&Ak[row][c]) =
                make_uint2(pack2(pf[i].x, pf[i].y), pack2(pf[i].z, pf[i].w));
        }
        __syncthreads();
        if (tt < 15) {
            const float* nb = akbase + (((size_t)(tt + 1)) << 12);
#pragma unroll
            for (int i = 0; i < 4; ++i) {
                int f = (i << 8) + t;
                pf[i] = *reinterpret_cast<const float4*>(&nb[((size_t)(f >> 4) << 6) + ((f & 15) << 2)]);
            }
        }
        short8 bb0 = *reinterpret_cast<const short8*>(&Ak[(w << 4) + lr][lg * 8]);
        short8 bb1 = *reinterpret_cast<const short8*>(&Ak[(w << 4) + lr][32 + lg * 8]);
        int kcol = (tt << 6) + (w << 4) + lr;
        f32x4 c;
#pragma unroll
        for (int r = 0; r < 4; ++r) c[r] = bf2f(Sc[scidx((lg << 2) + r, kcol)]);
        c = __builtin_amdgcn_mfma_f32_16x16x32_bf16(qa0, bb0, c, 0, 0, 0);
        c = __builtin_amdgcn_mfma_f32_16x16x32_bf16(qa1, bb1, c, 0, 0, 0);
#pragma unroll
        for (int r = 0; r < 4; ++r) Sc[scidx((lg << 2) + r, kcol)] = f2bf(c[r]);
    }
    __syncthreads();

    // ---- softmax (rows = 16 batches; 16 threads per row)
    {
        int row = t >> 4, ch = t & 15;
        float m = -1e30f;
#pragma unroll
        for (int i = 0; i < 8; ++i) {
            ushort8 v = *reinterpret_cast<const ushort8*>(&Sc[scidx(row, (ch << 6) + (i << 3))]);
#pragma unroll
            for (int j = 0; j < 8; ++j) m = fmaxf(m, bf2f(v[j]));
        }
#pragma unroll
        for (int d = 1; d < 16; d <<= 1) m = fmaxf(m, __shfl_xor(m, d));
        float s = 0.f;
#pragma unroll
        for (int i = 0; i < 8; ++i) {
            int idx = scidx(row, (ch << 6) + (i << 3));
            ushort8 v = *reinterpret_cast<const ushort8*>(&Sc[idx]);
            ushort8 e;
#pragma unroll
            for (int j = 0; j < 8; ++j) {
                float ev = exp2f(bf2f(v[j]) - m);
                s += ev;
                e[j] = f2bf(ev);
            }
            *reinterpret_cast<ushort8*>(&Sc[idx]) = e;
        }
#pragma unroll
        for (int d = 1; d < 16; d <<= 1) s += __shfl_xor(s, d);
        float inv = 1.0f / s;
        if (ch == 0) invs[row] = inv;
#pragma unroll
        for (int i = 0; i < 8; ++i) {
            int k = (ch << 6) + (i << 3);
            ushort8 v = *reinterpret_cast<const ushort8*>(&Sc[scidx(row, k)]);
            float4 o0 = make_float4(bf2f(v[0]) * inv, bf2f(v[1]) * inv, bf2f(v[2]) * inv, bf2f(v[3]) * inv);
            float4 o1 = make_float4(bf2f(v[4]) * inv, bf2f(v[5]) * inv, bf2f(v[6]) * inv, bf2f(v[7]) * inv);
            float* dst = &attn[((size_t)((b0 + row) * S_ + q) << 10) + k];
            *reinterpret_cast<float4*>(dst) = o0;
            *reinterpret_cast<float4*>(dst + 4) = o1;
        }
    }

    // ---- phase B: out_rel = (e . a_value[q]) * inv
    const float* avbase = &AV[(size_t)q << 16];
#pragma unroll
    for (int i = 0; i < 4; ++i) {
        int f = (i << 8) + t;
        pf[i] = *reinterpret_cast<const float4*>(&avbase[((size_t)(f >> 4) << 6) + ((f & 15) << 2)]);
    }
    f32x4 oacc = {};
    for (int tt = 0; tt < 16; ++tt) {
        __syncthreads();
#pragma unroll
        for (int i = 0; i < 4; ++i) tpose_store(Ak, pf[i], i, t);
        __syncthreads();
        if (tt < 15) {
            const float* nb = avbase + (((size_t)(tt + 1)) << 12);
#pragma unroll
            for (int i = 0; i < 4; ++i) {
                int f = (i << 8) + t;
                pf[i] = *reinterpret_cast<const float4*>(&nb[((size_t)(f >> 4) << 6) + ((f & 15) << 2)]);
            }
        }
        short8 bb0 = *reinterpret_cast<const short8*>(&Ak[(w << 4) + lr][lg * 8]);
        short8 bb1 = *reinterpret_cast<const short8*>(&Ak[(w << 4) + lr][32 + lg * 8]);
        short8 ea0 = *reinterpret_cast<const short8*>(&Sc[scidx(lr, (tt << 6) + lg * 8)]);
        short8 ea1 = *reinterpret_cast<const short8*>(&Sc[scidx(lr, (tt << 6) + 32 + lg * 8)]);
        oacc = __builtin_amdgcn_mfma_f32_16x16x32_bf16(ea0, bb0, oacc, 0, 0, 0);
        oacc = __builtin_amdgcn_mfma_f32_16x16x32_bf16(ea1, bb1, oacc, 0, 0, 0);
    }
#pragma unroll
    for (int r = 0; r < 4; ++r) {
        int brow = (lg << 2) + r;
        outp[((size_t)((b0 + brow) * S_ + q) << 6) + (w << 4) + lr] = oacc[r] * invs[brow];
    }
}

// ---------------- K3: out += attn[b] . V[b]
__global__ __launch_bounds__(256) void k3_pv(const float* __restrict__ V,
                                             const float* __restrict__ attn,
                                             float* __restrict__ outp) {
    __shared__ __align__(16) unsigned short At[64][72];
    __shared__ __align__(16) unsigned short Vt[64][72];
    const int b  = blockIdx.x >> 4;
    const int q0 = (blockIdx.x & 15) << 6;
    const int t  = threadIdx.x;
    const int l = t & 63, w = t >> 6, lr = l & 15, lg = l >> 4;
    float4 pa[4], pv[4];
#pragma unroll
    for (int i = 0; i < 4; ++i) {
        int f = (i << 8) + t;
        int row = f >> 4, c = (f & 15) << 2;
        pa[i] = *reinterpret_cast<const float4*>(&attn[((size_t)(b * S_ + q0 + row) << 10) + c]);
        pv[i] = *reinterpret_cast<const float4*>(&V[((size_t)(b * S_ + row) << 6) + c]);
    }
    f32x4 acc[4] = {};
    for (int tt = 0; tt < 16; ++tt) {
        __syncthreads();
#pragma unroll
        for (int i = 0; i < 4; ++i) {
            int f = (i << 8) + t;
            int row = f >> 4, c = (f & 15) << 2;
            *reinterpret_cast<uint2*>(&At[row][c]) =
                make_uint2(pack2(pa[i].x, pa[i].y), pack2(pa[i].z, pa[i].w));
            tpose_store(Vt, pv[i], i, t);
        }
        __syncthreads();
        if (tt < 15) {
#pragma unroll
            for (int i = 0; i < 4; ++i) {
                int f = (i << 8) + t;
                int row = f >> 4, c = (f & 15) << 2;
                pa[i] = *reinterpret_cast<const float4*>(
                    &attn[((size_t)(b * S_ + q0 + row) << 10) + ((tt + 1) << 6) + c]);
                pv[i] = *reinterpret_cast<const float4*>(
                    &V[((size_t)(b * S_ + ((tt + 1) << 6) + row) << 6) + c]);
            }
        }
        short8 a0 = *reinterpret_cast<const short8*>(&At[(w << 4) + lr][lg * 8]);
        short8 a1 = *reinterpret_cast<const short8*>(&At[(w << 4) + lr][32 + lg * 8]);
#pragma unroll
        for (int n = 0; n < 4; ++n) {
            short8 b0 = *reinterpret_cast<const short8*>(&Vt[(n << 4) + lr][lg * 8]);
            short8 b1 = *reinterpret_cast<const short8*>(&Vt[(n << 4) + lr][32 + lg * 8]);
            acc[n] = __builtin_amdgcn_mfma_f32_16x16x32_bf16(a0, b0, acc[n], 0, 0, 0);
            acc[n] = __builtin_amdgcn_mfma_f32_16x16x32_bf16(a1, b1, acc[n], 0, 0, 0);
        }
    }
#pragma unroll
    for (int n = 0; n < 4; ++n)
#pragma unroll
        for (int r = 0; r < 4; ++r) {
            size_t idx = ((size_t)(b * S_ + q0 + (w << 4) + (lg << 2) + r) << 6) + (n << 4) + lr;
            outp[idx] += acc[n][r];
        }
}

extern "C" void kernel_launch(void* const* d_in, const int* in_sizes, int n_in,
                              void* d_out, int out_size, void* d_ws, size_t ws_size,
                              hipStream_t stream) {
    (void)in_sizes; (void)n_in; (void)out_size; (void)d_ws; (void)ws_size;
    const float* Q  = (const float*)d_in[0];
    const float* K  = (const float*)d_in[1];
    const float* V  = (const float*)d_in[2];
    const float* AK = (const float*)d_in[3];
    const float* AV = (const float*)d_in[4];
    float* outp = (float*)d_out;
    float* attn = outp + (size_t)B_ * S_ * D_;

    k1_qk <<<dim3(64 * 8 * 8), dim3(256), 0, stream>>>(Q, K, attn);
    k2_mid<<<dim3(1024 * 4),   dim3(256), 0, stream>>>(Q, AK, AV, attn, outp);
    k3_pv <<<dim3(64 * 16),    dim3(256), 0, stream>>>(V, attn, outp);
}

// Round 2
// 425.707 us; speedup vs baseline: 1.3228x; 1.3228x over previous
//
#include <hip/hip_runtime.h>
#include <stdint.h>

#define S_ 1024
#define D_ 64
#define B_ 64

typedef short short8 __attribute__((ext_vector_type(8)));
typedef unsigned short ushort8 __attribute__((ext_vector_type(8)));
typedef float f32x4 __attribute__((ext_vector_type(4)));

__device__ __forceinline__ unsigned short f2bf(float x) {
    uint32_t u = __builtin_bit_cast(uint32_t, x);
    return (unsigned short)((u + 0x7FFFu + ((u >> 16) & 1u)) >> 16);
}
__device__ __forceinline__ float bf2f(unsigned short b) {
    return __builtin_bit_cast(float, ((uint32_t)b) << 16);
}
__device__ __forceinline__ uint32_t pack2(float a, float b) {
    return (uint32_t)f2bf(a) | ((uint32_t)f2bf(b) << 16);
}
// XOR-swizzled index into the 32x1024 bf16 score buffer (16B-chunk swizzle by row&15)
__device__ __forceinline__ int scidx(int row, int k) {
    return (((row << 10) + (k & ~7)) ^ ((row & 15) << 3)) + (k & 7);
}

// ---------------- K1: qk[b,q,k] = Q[b,q,:].K[b,k,:]  (writes f32 into attn region)
__global__ __launch_bounds__(256) void k1_qk(const float* __restrict__ Q,
                                             const float* __restrict__ Kk,
                                             float* __restrict__ qk) {
    __shared__ __align__(16) unsigned short Qs[128][72];
    __shared__ __align__(16) unsigned short Ks[128][72];
    const int bx = blockIdx.x;
    const int b  = bx >> 6;
    const int q0 = ((bx >> 3) & 7) << 7;
    const int k0 = (bx & 7) << 7;
    const int t  = threadIdx.x;
#pragma unroll
    for (int i = 0; i < 8; ++i) {
        int f = (i << 8) + t;
        int row = f >> 4, c = (f & 15) << 2;
        float4 v = *reinterpret_cast<const float4*>(&Q[((size_t)(b * S_ + q0 + row) << 6) + c]);
        *reinterpret_cast<uint2*>(&Qs[row][c]) = make_uint2(pack2(v.x, v.y), pack2(v.z, v.w));
        float4 u = *reinterpret_cast<const float4*>(&Kk[((size_t)(b * S_ + k0 + row) << 6) + c]);
        *reinterpret_cast<uint2*>(&Ks[row][c]) = make_uint2(pack2(u.x, u.y), pack2(u.z, u.w));
    }
    __syncthreads();
    const int l = t & 63, w = t >> 6, lr = l & 15, lg = l >> 4;
    short8 a[2][2];
#pragma unroll
    for (int mi = 0; mi < 2; ++mi)
#pragma unroll
        for (int h = 0; h < 2; ++h)
            a[mi][h] = *reinterpret_cast<const short8*>(&Qs[((w * 2 + mi) << 4) + lr][h * 32 + lg * 8]);
    f32x4 acc[2][8] = {};
#pragma unroll
    for (int n = 0; n < 8; ++n) {
        short8 b0 = *reinterpret_cast<const short8*>(&Ks[(n << 4) + lr][lg * 8]);
        short8 b1 = *reinterpret_cast<const short8*>(&Ks[(n << 4) + lr][32 + lg * 8]);
#pragma unroll
        for (int mi = 0; mi < 2; ++mi) {
            acc[mi][n] = __builtin_amdgcn_mfma_f32_16x16x32_bf16(a[mi][0], b0, acc[mi][n], 0, 0, 0);
            acc[mi][n] = __builtin_amdgcn_mfma_f32_16x16x32_bf16(a[mi][1], b1, acc[mi][n], 0, 0, 0);
        }
    }
#pragma unroll
    for (int mi = 0; mi < 2; ++mi)
#pragma unroll
        for (int n = 0; n < 8; ++n)
#pragma unroll
            for (int r = 0; r < 4; ++r) {
                int qq = q0 + ((w * 2 + mi) << 4) + (lg << 2) + r;
                int kc = k0 + (n << 4) + lr;
                qk[((size_t)(b * S_ + qq) << 10) + kc] = acc[mi][n][r];
            }
}

// in-register 4x4 transpose (lanes l, l^16, l^32, l^48) then b64 LDS store: T[d][k]
__device__ __forceinline__ void tpose_store(unsigned short (*Tls)[72], float4 p,
                                            int i, int t) {
    const int l = t & 63, w = t >> 6, lr = l & 15, lg = l >> 4;
    float v0 = p.x, v1 = p.y, v2 = p.z, v3 = p.w;
    float y0 = __shfl_xor(v0, 16), y1 = __shfl_xor(v1, 16),
          y2 = __shfl_xor(v2, 16), y3 = __shfl_xor(v3, 16);
    bool o = (lg & 1);
    float n0 = o ? y1 : v0, n1 = o ? v1 : y0, n2 = o ? y3 : v2, n3 = o ? v3 : y2;
    float z0 = __shfl_xor(n0, 32), z1 = __shfl_xor(n1, 32),
          z2 = __shfl_xor(n2, 32), z3 = __shfl_xor(n3, 32);
    bool h = (lg & 2);
    float T0 = h ? z2 : n0, T1 = h ? z3 : n1, T2 = h ? n2 : z0, T3 = h ? n3 : z1;
    int d = (lr << 2) + lg, kb = (i << 4) + (w << 2);
    *reinterpret_cast<uint2*>(&Tls[d][kb]) = make_uint2(pack2(T0, T1), pack2(T2, T3));
}

// ---------------- K2: per (q, 32-batch group): rel scores + softmax + attn + rel_qkv
__global__ __launch_bounds__(256) void k2_mid(const float* __restrict__ Q,
                                              const float* __restrict__ AK,
                                              const float* __restrict__ AV,
                                              float* __restrict__ attn,
                                              float* __restrict__ outp) {
    __shared__ __align__(16) unsigned short Sc[32 * 1024];
    __shared__ __align__(16) unsigned short Qs[32][72];
    __shared__ __align__(16) unsigned short Ak[64][72];
    __shared__ float invs[32];
    const float SCL = 0.18033688011112042f;  // log2(e)/8
    // XCD-pair swizzle: the 2 blocks sharing q land on the same XCD, 8 apart.
    const int j = blockIdx.x;
    const int xcd = j & 7, slot = j >> 3;
    const int q  = xcd * 128 + (slot >> 1);
    const int b0 = (slot & 1) << 5;
    const int t  = threadIdx.x;
    const int l = t & 63, w = t >> 6, lr = l & 15, lg = l >> 4;

#pragma unroll
    for (int i = 0; i < 2; ++i) {   // Qs (pre-scaled by SCL), 32 rows x 64
        int f = (i << 8) + t;
        int row = f >> 4, c = (f & 15) << 2;
        float4 v = *reinterpret_cast<const float4*>(&Q[((size_t)((b0 + row) * S_ + q) << 6) + c]);
        *reinterpret_cast<uint2*>(&Qs[row][c]) =
            make_uint2(pack2(v.x * SCL, v.y * SCL), pack2(v.z * SCL, v.w * SCL));
    }
#pragma unroll
    for (int i = 0; i < 32; ++i) {   // init Sc = qk * SCL  (row i, col t*4)
        int col = t << 2;
        float4 v = *reinterpret_cast<const float4*>(&attn[((size_t)((b0 + i) * S_ + q) << 10) + col]);
        *reinterpret_cast<uint2*>(&Sc[scidx(i, col)]) =
            make_uint2(pack2(v.x * SCL, v.y * SCL), pack2(v.z * SCL, v.w * SCL));
    }
    const float* akbase = &AK[(size_t)q << 16];
    float4 pf[4];
#pragma unroll
    for (int i = 0; i < 4; ++i) {
        int f = (i << 8) + t;
        pf[i] = *reinterpret_cast<const float4*>(&akbase[((size_t)(f >> 4) << 6) + ((f & 15) << 2)]);
    }
    __syncthreads();

    // ---- phase A: scores += (Q*SCL) . a_key[q]^T   M=32 N=64/iter K=64
    short8 qa[2][2];
#pragma unroll
    for (int mi = 0; mi < 2; ++mi)
#pragma unroll
        for (int h = 0; h < 2; ++h)
            qa[mi][h] = *reinterpret_cast<const short8*>(&Qs[(mi << 4) + lr][(h << 5) + (lg << 3)]);

    for (int tt = 0; tt < 16; ++tt) {
        __syncthreads();
#pragma unroll
        for (int i = 0; i < 4; ++i) {
            int f = (i << 8) + t;
            int row = f >> 4, c = (f & 15) << 2;
            *reinterpret_cast<uint2*>(&Ak[row][c]) =
                make_uint2(pack2(pf[i].x, pf[i].y), pack2(pf[i].z, pf[i].w));
        }
        __syncthreads();
        if (tt < 15) {
            const float* nb = akbase + (((size_t)(tt + 1)) << 12);
#pragma unroll
            for (int i = 0; i < 4; ++i) {
                int f = (i << 8) + t;
                pf[i] = *reinterpret_cast<const float4*>(&nb[((size_t)(f >> 4) << 6) + ((f & 15) << 2)]);
            }
        }
        short8 bb0 = *reinterpret_cast<const short8*>(&Ak[(w << 4) + lr][lg << 3]);
        short8 bb1 = *reinterpret_cast<const short8*>(&Ak[(w << 4) + lr][32 + (lg << 3)]);
        int kcol = (tt << 6) + (w << 4) + lr;
#pragma unroll
        for (int mi = 0; mi < 2; ++mi) {
            f32x4 c;
#pragma unroll
            for (int r = 0; r < 4; ++r) c[r] = bf2f(Sc[scidx((mi << 4) + (lg << 2) + r, kcol)]);
            c = __builtin_amdgcn_mfma_f32_16x16x32_bf16(qa[mi][0], bb0, c, 0, 0, 0);
            c = __builtin_amdgcn_mfma_f32_16x16x32_bf16(qa[mi][1], bb1, c, 0, 0, 0);
#pragma unroll
            for (int r = 0; r < 4; ++r) Sc[scidx((mi << 4) + (lg << 2) + r, kcol)] = f2bf(c[r]);
        }
    }
    __syncthreads();

    // ---- softmax: 32 rows, 8 threads/row, interleaved chunks (bank-balanced)
    {
        int row = t >> 3, ch = t & 7;
        float m = -1e30f;
#pragma unroll
        for (int i = 0; i < 16; ++i) {
            int k = (((i << 3) + ch) << 3);
            ushort8 v = *reinterpret_cast<const ushort8*>(&Sc[scidx(row, k)]);
#pragma unroll
            for (int jj = 0; jj < 8; ++jj) m = fmaxf(m, bf2f(v[jj]));
        }
#pragma unroll
        for (int d = 1; d < 8; d <<= 1) m = fmaxf(m, __shfl_xor(m, d));
        float s = 0.f;
#pragma unroll
        for (int i = 0; i < 16; ++i) {
            int k = (((i << 3) + ch) << 3);
            int idx = scidx(row, k);
            ushort8 v = *reinterpret_cast<const ushort8*>(&Sc[idx]);
            ushort8 e;
#pragma unroll
            for (int jj = 0; jj < 8; ++jj) {
                float ev = exp2f(bf2f(v[jj]) - m);
                s += ev;
                e[jj] = f2bf(ev);
            }
            *reinterpret_cast<ushort8*>(&Sc[idx]) = e;
        }
#pragma unroll
        for (int d = 1; d < 8; d <<= 1) s += __shfl_xor(s, d);
        float inv = 1.0f / s;
        if (ch == 0) invs[row] = inv;
    }
    __syncthreads();

    // prefetch first AV tile, then write attn (coalesced, row-uniform)
    const float* avbase = &AV[(size_t)q << 16];
#pragma unroll
    for (int i = 0; i < 4; ++i) {
        int f = (i << 8) + t;
        pf[i] = *reinterpret_cast<const float4*>(&avbase[((size_t)(f >> 4) << 6) + ((f & 15) << 2)]);
    }
#pragma unroll
    for (int i = 0; i < 32; ++i) {
        int col = t << 2;
        uint2 u = *reinterpret_cast<const uint2*>(&Sc[scidx(i, col)]);
        float inv = invs[i];
        float4 o = make_float4(bf2f((unsigned short)(u.x & 0xffff)) * inv,
                               bf2f((unsigned short)(u.x >> 16)) * inv,
                               bf2f((unsigned short)(u.y & 0xffff)) * inv,
                               bf2f((unsigned short)(u.y >> 16)) * inv);
        *reinterpret_cast<float4*>(&attn[((size_t)((b0 + i) * S_ + q) << 10) + col]) = o;
    }

    // ---- phase B: out_rel = (e . a_value[q]) * inv   M=32 N=64 K=1024
    f32x4 oacc[2] = {};
    for (int tt = 0; tt < 16; ++tt) {
        __syncthreads();
#pragma unroll
        for (int i = 0; i < 4; ++i) tpose_store(Ak, pf[i], i, t);
        __syncthreads();
        if (tt < 15) {
            const float* nb = avbase + (((size_t)(tt + 1)) << 12);
#pragma unroll
            for (int i = 0; i < 4; ++i) {
                int f = (i << 8) + t;
                pf[i] = *reinterpret_cast<const float4*>(&nb[((size_t)(f >> 4) << 6) + ((f & 15) << 2)]);
            }
        }
        short8 bb0 = *reinterpret_cast<const short8*>(&Ak[(w << 4) + lr][lg << 3]);
        short8 bb1 = *reinterpret_cast<const short8*>(&Ak[(w << 4) + lr][32 + (lg << 3)]);
#pragma unroll
        for (int mi = 0; mi < 2; ++mi) {
            short8 ea0 = *reinterpret_cast<const short8*>(&Sc[scidx((mi << 4) + lr, (tt << 6) + (lg << 3))]);
            short8 ea1 = *reinterpret_cast<const short8*>(&Sc[scidx((mi << 4) + lr, (tt << 6) + 32 + (lg << 3))]);
            oacc[mi] = __builtin_amdgcn_mfma_f32_16x16x32_bf16(ea0, bb0, oacc[mi], 0, 0, 0);
            oacc[mi] = __builtin_amdgcn_mfma_f32_16x16x32_bf16(ea1, bb1, oacc[mi], 0, 0, 0);
        }
    }
#pragma unroll
    for (int mi = 0; mi < 2; ++mi)
#pragma unroll
        for (int r = 0; r < 4; ++r) {
            int brow = (mi << 4) + (lg << 2) + r;
            outp[((size_t)((b0 + brow) * S_ + q) << 6) + (w << 4) + lr] = oacc[mi][r] * invs[brow];
        }
}

// ---------------- K3: out += attn[b] . V[b]
__global__ __launch_bounds__(256) void k3_pv(const float* __restrict__ V,
                                             const float* __restrict__ attn,
                                             float* __restrict__ outp) {
    __shared__ __align__(16) unsigned short At[64][72];
    __shared__ __align__(16) unsigned short Vt[64][72];
    const int b  = blockIdx.x >> 4;
    const int q0 = (blockIdx.x & 15) << 6;
    const int t  = threadIdx.x;
    const int l = t & 63, w = t >> 6, lr = l & 15, lg = l >> 4;
    float4 pa[4], pv[4];
#pragma unroll
    for (int i = 0; i < 4; ++i) {
        int f = (i << 8) + t;
        int row = f >> 4, c = (f & 15) << 2;
        pa[i] = *reinterpret_cast<const float4*>(&attn[((size_t)(b * S_ + q0 + row) << 10) + c]);
        pv[i] = *reinterpret_cast<const float4*>(&V[((size_t)(b * S_ + row) << 6) + c]);
    }
    f32x4 acc[4] = {};
    for (int tt = 0; tt < 16; ++tt) {
        __syncthreads();
#pragma unroll
        for (int i = 0; i < 4; ++i) {
            int f = (i << 8) + t;
            int row = f >> 4, c = (f & 15) << 2;
            *reinterpret_cast<uint2*>(&At[row][c]) =
                make_uint2(pack2(pa[i].x, pa[i].y), pack2(pa[i].z, pa[i].w));
            tpose_store(Vt, pv[i], i, t);
        }
        __syncthreads();
        if (tt < 15) {
#pragma unroll
            for (int i = 0; i < 4; ++i) {
                int f = (i << 8) + t;
                int row = f >> 4, c = (f & 15) << 2;
                pa[i] = *reinterpret_cast<const float4*>(
                    &attn[((size_t)(b * S_ + q0 + row) << 10) + ((tt + 1) << 6) + c]);
                pv[i] = *reinterpret_cast<const float4*>(
                    &V[((size_t)(b * S_ + ((tt + 1) << 6) + row) << 6) + c]);
            }
        }
        short8 a0 = *reinterpret_cast<const short8*>(&At[(w << 4) + lr][lg * 8]);
        short8 a1 = *reinterpret_cast<const short8*>(&At[(w << 4) + lr][32 + lg * 8]);
#pragma unroll
        for (int n = 0; n < 4; ++n) {
            short8 b0 = *reinterpret_cast<const short8*>(&Vt[(n << 4) + lr][lg * 8]);
            short8 b1 = *reinterpret_cast<const short8*>(&Vt[(n << 4) + lr][32 + lg * 8]);
            acc[n] = __builtin_amdgcn_mfma_f32_16x16x32_bf16(a0, b0, acc[n], 0, 0, 0);
            acc[n] = __builtin_amdgcn_mfma_f32_16x16x32_bf16(a1, b1, acc[n], 0, 0, 0);
        }
    }
#pragma unroll
    for (int n = 0; n < 4; ++n)
#pragma unroll
        for (int r = 0; r < 4; ++r) {
            size_t idx = ((size_t)(b * S_ + q0 + (w << 4) + (lg << 2) + r) << 6) + (n << 4) + lr;
            outp[idx] += acc[n][r];
        }
}

extern "C" void kernel_launch(void* const* d_in, const int* in_sizes, int n_in,
                              void* d_out, int out_size, void* d_ws, size_t ws_size,
                              hipStream_t stream) {
    (void)in_sizes; (void)n_in; (void)out_size; (void)d_ws; (void)ws_size;
    const float* Q  = (const float*)d_in[0];
    const float* K  = (const float*)d_in[1];
    const float* V  = (const float*)d_in[2];
    const float* AK = (const float*)d_in[3];
    const float* AV = (const float*)d_in[4];
    float* outp = (float*)d_out;
    float* attn = outp + (size_t)B_ * S_ * D_;

    k1_qk <<<dim3(64 * 8 * 8), dim3(256), 0, stream>>>(Q, K, attn);
    k2_mid<<<dim3(2048),       dim3(256), 0, stream>>>(Q, AK, AV, attn, outp);
    k3_pv <<<dim3(64 * 16),    dim3(256), 0, stream>>>(V, attn, outp);
}